// Round 2
// 182.713 us; speedup vs baseline: 1.0333x; 1.0333x over previous
//
#include <hip/hip_runtime.h>
#include <math.h>

#define N_NODES 100000
#define N_EDGES 6400000
#define K_BINS  5
#define BIN_SZ  20000          // N_NODES / K_BINS exactly; 80,000 B LDS -> 2 blocks/CU
#define BLOCK   1024
#define LOG2_10 3.321928094887362f

// Process one int4/float4 group of 4 edges: bin-match test + predicated
// rates[] gather + LDS atomic add.
__device__ __forceinline__ void proc4(const float* __restrict__ rates,
                                      float* __restrict__ bin, int base_node,
                                      int4 dd, int4 ss, float4 ww) {
    unsigned ex = (unsigned)(dd.x - base_node);
    unsigned ey = (unsigned)(dd.y - base_node);
    unsigned ez = (unsigned)(dd.z - base_node);
    unsigned ew = (unsigned)(dd.w - base_node);
    if (ex < BIN_SZ) atomicAdd(&bin[ex], rates[ss.x] * ww.x);
    if (ey < BIN_SZ) atomicAdd(&bin[ey], rates[ss.y] * ww.y);
    if (ez < BIN_SZ) atomicAdd(&bin[ez], rates[ss.z] * ww.z);
    if (ew < BIN_SZ) atomicAdd(&bin[ew], rates[ss.w] * ww.w);
}

// Each block owns (bin b, edge-chunk c). It scans chunk c's edges with vector
// loads, LDS-atomic-adds the edges landing in bin b, then flushes its 20k-float
// bin to a per-chunk private copy with float4 stores. No global atomics.
//
// R1 change: the kernel was latency-bound (VALUBusy 9%, HBM 36%, occupancy
// already maxed at 2 blocks/CU). Each thread now owns FOUR consecutive
// int4/float4 groups (16 edges) and issues all 12 independent stream loads
// before any dependent gather/atomic work -> ~4x memory-level parallelism.
// __launch_bounds__(1024, 8) keeps the allocator at <=64 VGPR so we hold
// 8 waves/EU (2 blocks/CU).
__global__ __launch_bounds__(BLOCK, 8) void edge_bin_kernel(
        const float* __restrict__ rates,
        const float* __restrict__ weights,
        const int* __restrict__ src,
        const int* __restrict__ dst,
        float* __restrict__ part,      // [n_chunks][N_NODES]
        int n_chunks, int edges_per_chunk) {
    __shared__ float bin[BIN_SZ];
    const int b = blockIdx.x % K_BINS; // adjacent blocks share the edge chunk
    const int c = blockIdx.x / K_BINS;
    const int base_node = b * BIN_SZ;

    // Vectorized zero-init: 20000 floats = 5000 float4 stores.
    {
        float4* bz = (float4*)bin;
        const float4 z = make_float4(0.f, 0.f, 0.f, 0.f);
        for (int i = threadIdx.x; i < (BIN_SZ >> 2); i += BLOCK) bz[i] = z;
    }
    __syncthreads();

    const long e0 = (long)c * edges_per_chunk;
    // edges_per_chunk % 16 == 0 for every chunk-count candidate, so the
    // quad-group decomposition is exact (no tail).
    const int nq = edges_per_chunk >> 4;              // groups of 16 edges
    const int4*   s4 = (const int4*)(src + e0);
    const int4*   d4 = (const int4*)(dst + e0);
    const float4* w4 = (const float4*)(weights + e0);

    for (int i = threadIdx.x; i < nq; i += BLOCK) {
        const int4*   dp = d4 + 4 * i;
        const int4*   sp = s4 + 4 * i;
        const float4* wp = w4 + 4 * i;
        // Issue all 12 independent stream loads before any dependent use.
        int4   d0 = dp[0], d1 = dp[1], d2 = dp[2], d3 = dp[3];
        int4   sA = sp[0], sB = sp[1], sC = sp[2], sD = sp[3];
        float4 wA = wp[0], wB = wp[1], wC = wp[2], wD = wp[3];
        proc4(rates, bin, base_node, d0, sA, wA);
        proc4(rates, bin, base_node, d1, sB, wB);
        proc4(rates, bin, base_node, d2, sC, wC);
        proc4(rates, bin, base_node, d3, sD, wD);
    }
    __syncthreads();

    // Vectorized flush: 20000 floats = 5000 float4s (ds_read_b128 + dwordx4).
    float4* outp = (float4*)(part + (size_t)c * N_NODES + base_node);
    const float4* binv = (const float4*)bin;
    for (int i = threadIdx.x; i < (BIN_SZ >> 2); i += BLOCK) {
        outp[i] = binv[i];
    }
}

// Node epilogue: sum the n_chunks copies, then
// out[v] = (-r + 10^gain * tanh((is_input ? ext : syn) + baseline)) / tau
// R1: 8 independent accumulator chains (was 4) + 128-thread blocks for
// better CU spread -- this kernel is also latency-bound (~6 waves/CU).
__global__ void node_kernel(const float* __restrict__ rates,
                            const float* __restrict__ gain,
                            const float* __restrict__ time_constant,
                            const float* __restrict__ baseline,
                            const float* __restrict__ ext_input,
                            const int*   __restrict__ is_input,
                            const float* __restrict__ part,
                            float* __restrict__ out,
                            int n_chunks) {
    int v = blockIdx.x * blockDim.x + threadIdx.x;
    if (v >= N_NODES) return;
    float s0 = 0.f, s1 = 0.f, s2 = 0.f, s3 = 0.f;
    float s4 = 0.f, s5 = 0.f, s6 = 0.f, s7 = 0.f;
    int k = 0;
    for (; k + 7 < n_chunks; k += 8) {
        s0 += part[(size_t)(k + 0) * N_NODES + v];
        s1 += part[(size_t)(k + 1) * N_NODES + v];
        s2 += part[(size_t)(k + 2) * N_NODES + v];
        s3 += part[(size_t)(k + 3) * N_NODES + v];
        s4 += part[(size_t)(k + 4) * N_NODES + v];
        s5 += part[(size_t)(k + 5) * N_NODES + v];
        s6 += part[(size_t)(k + 6) * N_NODES + v];
        s7 += part[(size_t)(k + 7) * N_NODES + v];
    }
    for (; k < n_chunks; ++k) s0 += part[(size_t)k * N_NODES + v];
    float s = ((s0 + s1) + (s2 + s3)) + ((s4 + s5) + (s6 + s7));
    float total = (is_input[v] != 0 ? ext_input[v] : s) + baseline[v];
    float act = tanhf(total);
    float g = exp2f(gain[v] * LOG2_10);   // 10^gain
    out[v] = (-rates[v] + g * act) / time_constant[v];
}

extern "C" void kernel_launch(void* const* d_in, const int* in_sizes, int n_in,
                              void* d_out, int out_size, void* d_ws, size_t ws_size,
                              hipStream_t stream) {
    const float* rates         = (const float*)d_in[0];
    const float* weights       = (const float*)d_in[1];
    const float* gain          = (const float*)d_in[2];
    const float* time_constant = (const float*)d_in[3];
    const float* baseline      = (const float*)d_in[4];
    const float* ext_input     = (const float*)d_in[5];
    const int*   src           = (const int*)d_in[6];
    const int*   dst           = (const int*)d_in[7];
    const int*   is_input      = (const int*)d_in[8];
    float* out  = (float*)d_out;
    float* part = (float*)d_ws;

    // Largest chunk count (from the preference list) whose partials fit d_ws.
    // 100 chunks -> 500 blocks ~= the 512-block residency capacity (2/CU).
    // All candidates give edges_per_chunk % 16 == 0 (needed for quad groups).
    static const int cand[] = {100, 50, 25, 20, 10, 5, 4, 2, 1};
    int n_chunks = 1;
    for (int i = 0; i < (int)(sizeof(cand)/sizeof(cand[0])); ++i) {
        if ((size_t)cand[i] * N_NODES * sizeof(float) <= ws_size) { n_chunks = cand[i]; break; }
    }
    int edges_per_chunk = N_EDGES / n_chunks;

    int grid_e = K_BINS * n_chunks;
    edge_bin_kernel<<<grid_e, BLOCK, 0, stream>>>(rates, weights, src, dst,
                                                  part, n_chunks, edges_per_chunk);

    int block = 128;
    int grid_n = (N_NODES + block - 1) / block;
    node_kernel<<<grid_n, block, 0, stream>>>(rates, gain, time_constant, baseline,
                                              ext_input, is_input, part, out, n_chunks);
}

// Round 3
// 174.481 us; speedup vs baseline: 1.0820x; 1.0472x over previous
//
#include <hip/hip_runtime.h>
#include <math.h>

#define N_NODES 100000
#define N_EDGES 6400000
#define K_BINS  5
#define BIN_SZ  20000          // N_NODES / K_BINS exactly; 80,000 B LDS -> 2 blocks/CU
#define BLOCK   1024
#define NXCD    8
#define LOG2_10 3.321928094887362f

// Process one int4/float4 group of 4 edges: bin-match test + predicated
// rates[] gather + LDS atomic add.
__device__ __forceinline__ void proc4(const float* __restrict__ rates,
                                      float* __restrict__ bin, int base_node,
                                      int4 dd, int4 ss, float4 ww) {
    unsigned ex = (unsigned)(dd.x - base_node);
    unsigned ey = (unsigned)(dd.y - base_node);
    unsigned ez = (unsigned)(dd.z - base_node);
    unsigned ew = (unsigned)(dd.w - base_node);
    if (ex < BIN_SZ) atomicAdd(&bin[ex], rates[ss.x] * ww.x);
    if (ey < BIN_SZ) atomicAdd(&bin[ey], rates[ss.y] * ww.y);
    if (ez < BIN_SZ) atomicAdd(&bin[ez], rates[ss.z] * ww.z);
    if (ew < BIN_SZ) atomicAdd(&bin[ew], rates[ss.w] * ww.w);
}

// Each block owns (bin b, edge-chunk c). It scans chunk c's edges with vector
// loads, LDS-atomic-adds the edges landing in bin b, then flushes its 20k-float
// bin to a per-chunk private copy with float4 stores. No global atomics.
//
// R3 change: XCD-aware bijective blockIdx swizzle (m204 variant). Without it,
// the 5 sibling bin-blocks of a chunk (consecutive blockIdx) round-robin onto
// 5 DIFFERENT XCDs, so the identical 768 KB edge chunk is fetched ~5x from
// HBM/L3 (measured FETCH 189 MB vs 77 MB unique). Grouping siblings on one
// XCD turns 4 of the 5 scans into ~200-cycle L2 hits -- this kernel is
// latency-bound (VALUBusy 8%, HBM 38%), so latency is the lever.
__global__ __launch_bounds__(BLOCK, 8) void edge_bin_kernel(
        const float* __restrict__ rates,
        const float* __restrict__ weights,
        const int* __restrict__ src,
        const int* __restrict__ dst,
        float* __restrict__ part,      // [n_chunks][N_NODES]
        int n_chunks, int edges_per_chunk) {
    __shared__ float bin[BIN_SZ];

    // Bijective XCD swizzle: hardware assigns XCD = hw_bid % NXCD.
    // Map so virtual ids are contiguous per XCD => the 5 siblings of a chunk
    // (vbid = 5c..5c+4) nearly always share an XCD.
    const int nb  = gridDim.x;
    const int hb  = blockIdx.x;
    const int q   = nb / NXCD, r = nb % NXCD;
    const int xcd = hb % NXCD, pos = hb / NXCD;
    const int vbid = (xcd < r ? xcd * (q + 1) : r * (q + 1) + (xcd - r) * q) + pos;

    const int b = vbid % K_BINS;
    const int c = vbid / K_BINS;
    const int base_node = b * BIN_SZ;

    // Vectorized zero-init: 20000 floats = 5000 float4 stores.
    {
        float4* bz = (float4*)bin;
        const float4 z = make_float4(0.f, 0.f, 0.f, 0.f);
        for (int i = threadIdx.x; i < (BIN_SZ >> 2); i += BLOCK) bz[i] = z;
    }
    __syncthreads();

    const long e0 = (long)c * edges_per_chunk;
    // edges_per_chunk % 16 == 0 for every chunk-count candidate, so the
    // quad-group decomposition is exact (no tail).
    const int nq = edges_per_chunk >> 4;              // groups of 16 edges
    const int4*   s4 = (const int4*)(src + e0);
    const int4*   d4 = (const int4*)(dst + e0);
    const float4* w4 = (const float4*)(weights + e0);

    for (int i = threadIdx.x; i < nq; i += BLOCK) {
        const int4*   dp = d4 + 4 * i;
        const int4*   sp = s4 + 4 * i;
        const float4* wp = w4 + 4 * i;
        // Issue independent stream loads before dependent use.
        int4   d0 = dp[0], d1 = dp[1], d2 = dp[2], d3 = dp[3];
        int4   sA = sp[0], sB = sp[1], sC = sp[2], sD = sp[3];
        float4 wA = wp[0], wB = wp[1], wC = wp[2], wD = wp[3];
        proc4(rates, bin, base_node, d0, sA, wA);
        proc4(rates, bin, base_node, d1, sB, wB);
        proc4(rates, bin, base_node, d2, sC, wC);
        proc4(rates, bin, base_node, d3, sD, wD);
    }
    __syncthreads();

    // Vectorized flush: 20000 floats = 5000 float4s (ds_read_b128 + dwordx4).
    float4* outp = (float4*)(part + (size_t)c * N_NODES + base_node);
    const float4* binv = (const float4*)bin;
    for (int i = threadIdx.x; i < (BIN_SZ >> 2); i += BLOCK) {
        outp[i] = binv[i];
    }
}

// Node epilogue: sum the n_chunks copies, then
// out[v] = (-r + 10^gain * tanh((is_input ? ext : syn) + baseline)) / tau
__global__ void node_kernel(const float* __restrict__ rates,
                            const float* __restrict__ gain,
                            const float* __restrict__ time_constant,
                            const float* __restrict__ baseline,
                            const float* __restrict__ ext_input,
                            const int*   __restrict__ is_input,
                            const float* __restrict__ part,
                            float* __restrict__ out,
                            int n_chunks) {
    int v = blockIdx.x * blockDim.x + threadIdx.x;
    if (v >= N_NODES) return;
    float s0 = 0.f, s1 = 0.f, s2 = 0.f, s3 = 0.f;
    float s4 = 0.f, s5 = 0.f, s6 = 0.f, s7 = 0.f;
    int k = 0;
    for (; k + 7 < n_chunks; k += 8) {
        s0 += part[(size_t)(k + 0) * N_NODES + v];
        s1 += part[(size_t)(k + 1) * N_NODES + v];
        s2 += part[(size_t)(k + 2) * N_NODES + v];
        s3 += part[(size_t)(k + 3) * N_NODES + v];
        s4 += part[(size_t)(k + 4) * N_NODES + v];
        s5 += part[(size_t)(k + 5) * N_NODES + v];
        s6 += part[(size_t)(k + 6) * N_NODES + v];
        s7 += part[(size_t)(k + 7) * N_NODES + v];
    }
    for (; k < n_chunks; ++k) s0 += part[(size_t)k * N_NODES + v];
    float s = ((s0 + s1) + (s2 + s3)) + ((s4 + s5) + (s6 + s7));
    float total = (is_input[v] != 0 ? ext_input[v] : s) + baseline[v];
    float act = tanhf(total);
    float g = exp2f(gain[v] * LOG2_10);   // 10^gain
    out[v] = (-rates[v] + g * act) / time_constant[v];
}

extern "C" void kernel_launch(void* const* d_in, const int* in_sizes, int n_in,
                              void* d_out, int out_size, void* d_ws, size_t ws_size,
                              hipStream_t stream) {
    const float* rates         = (const float*)d_in[0];
    const float* weights       = (const float*)d_in[1];
    const float* gain          = (const float*)d_in[2];
    const float* time_constant = (const float*)d_in[3];
    const float* baseline      = (const float*)d_in[4];
    const float* ext_input     = (const float*)d_in[5];
    const int*   src           = (const int*)d_in[6];
    const int*   dst           = (const int*)d_in[7];
    const int*   is_input      = (const int*)d_in[8];
    float* out  = (float*)d_out;
    float* part = (float*)d_ws;

    // Largest chunk count (from the preference list) whose partials fit d_ws.
    // 100 chunks -> 500 blocks ~= the 512-block residency capacity (2/CU).
    // All candidates give edges_per_chunk % 16 == 0 (needed for quad groups).
    static const int cand[] = {100, 50, 25, 20, 10, 5, 4, 2, 1};
    int n_chunks = 1;
    for (int i = 0; i < (int)(sizeof(cand)/sizeof(cand[0])); ++i) {
        if ((size_t)cand[i] * N_NODES * sizeof(float) <= ws_size) { n_chunks = cand[i]; break; }
    }
    int edges_per_chunk = N_EDGES / n_chunks;

    int grid_e = K_BINS * n_chunks;
    edge_bin_kernel<<<grid_e, BLOCK, 0, stream>>>(rates, weights, src, dst,
                                                  part, n_chunks, edges_per_chunk);

    int block = 256;
    int grid_n = (N_NODES + block - 1) / block;
    node_kernel<<<grid_n, block, 0, stream>>>(rates, gain, time_constant, baseline,
                                              ext_input, is_input, part, out, n_chunks);
}